// Round 9
// baseline (137.600 us; speedup 1.0000x reference)
//
#include <hip/hip_runtime.h>
#include <hip/hip_bf16.h>

// CumulativeLayerNorm: x [B=8, C=512, T=16000] f32 — 3-kernel L3-bounce.
// K1: per-t column sums s1=Σ_c x, q=Σ_c x² (reads x from HBM once, 250 MiB).
// K2: per-b hierarchical scan over t -> mean, istd (1 MB, ~5 µs).
// K3: normalize; x re-read hits L3 (streamed by K1 µs earlier, only ~2 MB of
//     workspace evicted since); nt-stores 250 MiB to HBM.
// No atomics, no spin: each kernel is a clean unidirectional stream.
// Workspace (floats): s1[B*T], q[B*T], mean[B*T], istd[B*T] (2 MB).

constexpr int Bb = 8;
constexpr int Cc = 512;
constexpr int Tt = 16000;
constexpr int T4 = Tt / 4;          // 4000
constexpr int TCH = 128;            // t per K1 block
constexpr int T4CH = TCH / 4;       // 32
constexpr int NCHK = Tt / TCH;      // 125
constexpr float EPSF = 1e-8f;

typedef float f32x4 __attribute__((ext_vector_type(4)));

__device__ __forceinline__ f32x4 shflx(f32x4 v, int m) {
    f32x4 r;
    r.x = __shfl_xor(v.x, m, 64);
    r.y = __shfl_xor(v.y, m, 64);
    r.z = __shfl_xor(v.z, m, 64);
    r.w = __shfl_xor(v.w, m, 64);
    return r;
}

// ---------------- K1: per-t column sums ----------------
__global__ __launch_bounds__(1024)
void colsum_kernel(const float* __restrict__ x,
                   float* __restrict__ s1g, float* __restrict__ qg)
{
    const int bid = blockIdx.x;
    const int k = bid >> 3;          // chunk 0..124
    const int b = bid & 7;
    const int tid = threadIdx.x;
    const int c_sub = tid >> 5;      // 0..31
    const int t4s   = tid & 31;      // 0..31
    const int lane  = tid & 63;
    const int wave  = tid >> 6;      // 0..15

    __shared__ f32x4 red_s[16][32], red_q[16][32];   // [wave][t4s] 16 KB

    const f32x4* xb = (const f32x4*)x + (size_t)(b * Cc + c_sub) * T4 + k * T4CH + t4s;
    f32x4 ps = 0, pq = 0;
    #pragma unroll
    for (int r = 0; r < 16; ++r) {
        const f32x4 v = xb[(size_t)r * 32 * T4];     // c = c_sub + 32*r
        ps += v;
        pq += v * v;
    }
    // fold the c_sub pair covered by this wave (lanes l and l^32 differ only in c)
    ps += shflx(ps, 32);
    pq += shflx(pq, 32);
    if (lane < 32) { red_s[wave][lane] = ps; red_q[wave][lane] = pq; }
    __syncthreads();

    if (tid < 32) {
        f32x4 sv = 0, qv = 0;
        #pragma unroll
        for (int w = 0; w < 16; ++w) {               // fixed order => deterministic
            sv += red_s[w][tid];
            qv += red_q[w][tid];
        }
        ((f32x4*)(s1g + (size_t)b * Tt + k * TCH))[tid] = sv;
        ((f32x4*)(qg  + (size_t)b * Tt + k * TCH))[tid] = qv;
    }
}

// ---------------- K2: per-batch scan, thread-serial 16/thread ----------------
#define SCAN_THREADS 1024

__device__ __forceinline__ float block_exscan(float val, int lane, int wave, float* lds)
{
    float sc = val;
    #pragma unroll
    for (int off = 1; off < 64; off <<= 1) {
        float n = __shfl_up(sc, off, 64);
        if (lane >= off) sc += n;
    }
    __syncthreads();
    if (lane == 63) lds[wave] = sc;
    __syncthreads();
    float pre = 0.f;
    #pragma unroll
    for (int w = 0; w < SCAN_THREADS / 64; ++w)
        if (w < wave) pre += lds[w];
    return pre + sc - val;           // exclusive prefix of this thread's val
}

__global__ __launch_bounds__(SCAN_THREADS)
void scan_kernel(const float* __restrict__ s1g, const float* __restrict__ qg,
                 float* __restrict__ meang, float* __restrict__ istdg)
{
    __shared__ float lds[SCAN_THREADS / 64];
    const int b    = blockIdx.x;
    const int tid  = threadIdx.x;
    const int lane = tid & 63;
    const int wave = tid >> 6;
    const float Cf = (float)Cc;

    const bool valid = tid < (Tt / 16);   // 1000 threads exactly cover T

    float s1v[16], qv[16];
    if (valid) {
        #pragma unroll
        for (int g = 0; g < 4; ++g) {
            const int idx = b * T4 + tid * 4 + g;
            const f32x4 a  = ((const f32x4*)s1g)[idx];
            const f32x4 qq = ((const f32x4*)qg)[idx];
            s1v[4*g+0] = a.x; s1v[4*g+1] = a.y; s1v[4*g+2] = a.z; s1v[4*g+3] = a.w;
            qv[4*g+0] = qq.x; qv[4*g+1] = qq.y; qv[4*g+2] = qq.z; qv[4*g+3] = qq.w;
        }
    } else {
        #pragma unroll
        for (int i = 0; i < 16; ++i) { s1v[i] = 0.f; qv[i] = 0.f; }
    }

    // ---- scan of s1 ----
    float lsum = 0.f;
    #pragma unroll
    for (int i = 0; i < 16; ++i) lsum += s1v[i];
    const float base1 = block_exscan(lsum, lane, wave, lds);

    float mean_r[16];
    float l2 = 0.f;
    {
        float cs = base1;
        #pragma unroll
        for (int i = 0; i < 16; ++i) {
            cs += s1v[i];
            const int t = tid * 16 + i;
            const float cnt = Cf * (float)(t + 1);
            const float mn = cs / cnt;
            mean_r[i] = mn;
            const float s2 = qv[i] - 2.f * mn * s1v[i] + Cf * mn * mn;
            qv[i] = s2;
            l2 += s2;
        }
    }
    if (!valid) l2 = 0.f;

    // ---- scan of s2 ----
    const float base2 = block_exscan(l2, lane, wave, lds);

    if (valid) {
        float cv = base2;
        float istd_r[16];
        #pragma unroll
        for (int i = 0; i < 16; ++i) {
            cv += qv[i];
            const int t = tid * 16 + i;
            const float cnt = Cf * (float)(t + 1);
            const float var = cv / cnt;
            istd_r[i] = rsqrtf(var + EPSF);
        }
        f32x4* mo = (f32x4*)(meang + (size_t)b * Tt) + tid * 4;
        f32x4* io = (f32x4*)(istdg + (size_t)b * Tt) + tid * 4;
        #pragma unroll
        for (int g = 0; g < 4; ++g) {
            f32x4 m, s;
            m.x = mean_r[4*g+0]; m.y = mean_r[4*g+1]; m.z = mean_r[4*g+2]; m.w = mean_r[4*g+3];
            s.x = istd_r[4*g+0]; s.y = istd_r[4*g+1]; s.z = istd_r[4*g+2]; s.w = istd_r[4*g+3];
            mo[g] = m;
            io[g] = s;
        }
    }
}

// ---------------- K3: normalize (x read from L3, nt-store out) ----------------
__global__ __launch_bounds__(256)
void normalize_kernel(const f32x4* __restrict__ x4,
                      const float* __restrict__ meang,
                      const float* __restrict__ istdg,
                      const float* __restrict__ gamma,
                      const float* __restrict__ beta,
                      f32x4* __restrict__ out4)
{
    const int bc = blockIdx.y;                // 0..B*C-1, ascending = K1's order
    const int c  = bc & (Cc - 1);
    const int b  = bc >> 9;                   // Cc = 512 = 2^9

    const f32x4* xr = x4 + (size_t)bc * T4;
    f32x4* outr     = out4 + (size_t)bc * T4;
    const f32x4* mr = (const f32x4*)(meang + (size_t)b * Tt);
    const f32x4* sr = (const f32x4*)(istdg + (size_t)b * Tt);

    const float g  = gamma[c];
    const float be = beta[c];

    #pragma unroll
    for (int it = 0; it < 4; ++it) {
        const int t4 = it * 1024 + blockIdx.x * 256 + threadIdx.x;
        if (t4 < T4) {
            const f32x4 xv = xr[t4];
            const f32x4 m4 = mr[t4];
            const f32x4 s4 = sr[t4];
            const f32x4 o = (xv - m4) * s4 * g + be;
            __builtin_nontemporal_store(o, &outr[t4]);
        }
    }
}

extern "C" void kernel_launch(void* const* d_in, const int* in_sizes, int n_in,
                              void* d_out, int out_size, void* d_ws, size_t ws_size,
                              hipStream_t stream) {
    const float* x     = (const float*)d_in[0];
    const float* gamma = (const float*)d_in[1];
    const float* beta  = (const float*)d_in[2];
    float* out = (float*)d_out;

    float* ws   = (float*)d_ws;
    float* s1   = ws;                        // B*T
    float* q    = s1 + (size_t)Bb * Tt;      // B*T
    float* mean = q  + (size_t)Bb * Tt;      // B*T
    float* istd = mean + (size_t)Bb * Tt;    // B*T

    // K1: column sums (reads x from HBM once)
    colsum_kernel<<<Bb * NCHK, 1024, 0, stream>>>(x, s1, q);

    // K2: scan (one block per batch)
    scan_kernel<<<Bb, SCAN_THREADS, 0, stream>>>(s1, q, mean, istd);

    // K3: normalize (x from L3)
    dim3 g3(4, Bb * Cc);
    normalize_kernel<<<g3, 256, 0, stream>>>(
        (const f32x4*)x, mean, istd, gamma, beta, (f32x4*)out);
}